// Round 2
// baseline (665.179 us; speedup 1.0000x reference)
//
#include <hip/hip_runtime.h>
#include <cmath>

// LabelSmoothKLDivLoss — closed form:
// loss = C + (1/N) * sum_i [ lse_i - PB*rowsum_i - (1-eps-PB)*x[i,y_i] ]
// C = eps*log(PB) + (1-eps)*log(1-eps)   (host, double precision)
//
// R1: rocprof showed the timed window is dominated by 2x 2GB
// fillBufferAligned dispatches (4.19GB @ 6.3TB/s = 666us ~= measured 664us)
// — the d_ws re-poison, NOT our kernel (which never entered the top-5,
// so it runs < 322us). This version eliminates the workspace entirely:
//   kernel 1: out[0] = C
//   kernel 2: 1024 blocks x 4 rows, block-reduce per row, ONE
//             atomicAdd(out, acc/N) per block (1024 same-address atomics).
// If the 2GB poison was ws-conditional, dur_us should collapse to the
// kernel's true ~110-160us. If not, we learn the floor is harness traffic.

#define NCLASS 32000
#define NROWS  4096
#define NVEC   (NCLASS / 4)   // 8000 float4 per row
#define ROWS_PER_BLOCK 4
#define NBLOCKS (NROWS / ROWS_PER_BLOCK)   // 1024

constexpr float EPSILON_F = 0.1f;
constexpr float PB_F      = 0.1f / 31999.0f;
constexpr float LOG2E_F   = 1.44269504088896340736f;
constexpr float SHIFT2_F  = 16.0f * 1.44269504088896340736f;  // shift in exp2 domain
constexpr float LN2_F     = 0.69314718055994530942f;

typedef float vf4 __attribute__((ext_vector_type(4)));

__device__ __forceinline__ void acc_update(vf4 v, float& s, float& rs) {
    // e = exp(x - 16) computed as exp2(x*log2e - 16*log2e): 1 fma + 1 v_exp_f32
    float e0 = __builtin_amdgcn_exp2f(__builtin_fmaf(v.x, LOG2E_F, -SHIFT2_F));
    float e1 = __builtin_amdgcn_exp2f(__builtin_fmaf(v.y, LOG2E_F, -SHIFT2_F));
    float e2 = __builtin_amdgcn_exp2f(__builtin_fmaf(v.z, LOG2E_F, -SHIFT2_F));
    float e3 = __builtin_amdgcn_exp2f(__builtin_fmaf(v.w, LOG2E_F, -SHIFT2_F));
    s  += (e0 + e1) + (e2 + e3);
    rs += (v.x + v.y) + (v.z + v.w);
}

__global__ void ls_init_out(float* __restrict__ out, float C) {
    out[0] = C;
}

__global__ __launch_bounds__(256, 8)
void ls_kldiv_fused_kernel(const float* __restrict__ x,
                           const int*   __restrict__ y,
                           float*       __restrict__ out) {
    const int tid  = threadIdx.x;
    const int wave = tid >> 6;
    const int lane = tid & 63;
    const int row0 = blockIdx.x * ROWS_PER_BLOCK;

    __shared__ float ss[4], srs[4];

    float acc = 0.f;   // meaningful on tid 0 only

    for (int r = 0; r < ROWS_PER_BLOCK; ++r) {
        const int row = row0 + r;
        const vf4* __restrict__ xr =
            reinterpret_cast<const vf4*>(x + (size_t)row * NCLASS);

        // Hoist target-class load: overlaps the streaming loop below.
        float xy = 0.f;
        if (tid == 0) {
            xy = x[(size_t)row * NCLASS + y[row]];
        }

        float s0 = 0.f, s1 = 0.f, s2 = 0.f, s3 = 0.f;
        float r0 = 0.f, r1 = 0.f, r2 = 0.f, r3 = 0.f;

        int base = tid;
        // full 4-wide chunks: all four loads in-bounds
        for (; base + 768 < NVEC; base += 1024) {
            vf4 v0 = xr[base];
            vf4 v1 = xr[base + 256];
            vf4 v2 = xr[base + 512];
            vf4 v3 = xr[base + 768];
            acc_update(v0, s0, r0);
            acc_update(v1, s1, r1);
            acc_update(v2, s2, r2);
            acc_update(v3, s3, r3);
        }
        // tail: single-stream
        for (; base < NVEC; base += 256) {
            vf4 v = xr[base];
            acc_update(v, s0, r0);
        }

        float s  = (s0 + s1) + (s2 + s3);
        float rs = (r0 + r1) + (r2 + r3);

        // wave (64-lane) butterfly reduction
        #pragma unroll
        for (int off = 1; off < 64; off <<= 1) {
            s  += __shfl_xor(s,  off);
            rs += __shfl_xor(rs, off);
        }

        if (lane == 0) { ss[wave] = s; srs[wave] = rs; }
        __syncthreads();

        if (tid == 0) {
            s  = (ss[0]  + ss[1])  + (ss[2]  + ss[3]);
            rs = (srs[0] + srs[1]) + (srs[2] + srs[3]);
            // lse = 16 + ln(sum exp(x-16)) == LN2 * (SHIFT2 + log2(s))
            float lse = LN2_F * (SHIFT2_F + __builtin_amdgcn_logf(s));
            acc += lse - PB_F * rs - (1.0f - EPSILON_F - PB_F) * xy;
        }
        __syncthreads();   // ss/srs reused next row
    }

    if (tid == 0) {
        atomicAdd(out, acc * (1.0f / (float)NROWS));
    }
}

extern "C" void kernel_launch(void* const* d_in, const int* in_sizes, int n_in,
                              void* d_out, int out_size, void* d_ws, size_t ws_size,
                              hipStream_t stream) {
    const float* x = (const float*)d_in[0];
    const int*   y = (const int*)d_in[1];
    float* out     = (float*)d_out;
    (void)d_ws; (void)ws_size;   // workspace intentionally unused (see R1 note)

    const double eps = 0.1;
    const double pb  = eps / (32000.0 - 1.0);
    const float  C   = (float)(eps * log(pb) + (1.0 - eps) * log(1.0 - eps));

    ls_init_out<<<1, 1, 0, stream>>>(out, C);
    ls_kldiv_fused_kernel<<<NBLOCKS, 256, 0, stream>>>(x, y, out);
}